// Round 11
// baseline (81.853 us; speedup 1.0000x reference)
//
#include <hip/hip_runtime.h>

// Conv4D (2,8,7,7,48,48) fp32, 3x3x3x3 pad 1, 8->8 ch — bf16 MFMA implicit GEMM.
// R10: R8b (full-M d-packing, 2 dtiles/wave) + K-split by slice parity across
// gridDim.z=2 -> 7056 waves (27.6/CU), partial sums combined via f32 HW atomics.
// Bias pre-written to out by prep; main kernel atomic-adds its half-K partial.
//
// d_ws layout (re-poisoned each launch; fully rewritten by prep):
//   [0,       3920000)  xp: bf16 x as [b][uv 49][hh 50][ww 50][c 8], halo zeros
//   [3920000, 3960000)  zero slice (40 KB) backing invalid (u,v) slices
//   [3960000, 3987648)  Wp2: A-frags [aslot 27 = i0i1*3+i3][lane 64][j 8] bf16
//                       Wp2[as][lane][j] = W[o=m&7, i0i1, i2=q-d, i3, c=j],
//                       m=lane&15, q=lane>>4, d=m>>3; zero if q-d not in 0..2
//   [3987648, 3991176)  tbl: [img 98][k 9] i32 = uvbase | (i0i1 << 22)
//                       (entries 0..nv-1 real, nv..8 -> zero slice)

typedef __attribute__((ext_vector_type(8))) short short8;
typedef __attribute__((ext_vector_type(4))) float f32x4;

#define CSTRIDE (49 * 2304)
#define ZS_OFF  3920000
#define WP_OFF  3960000
#define WT_OFF  3987648

__device__ __forceinline__ unsigned short f2bf(float f) {
    union { float f; unsigned u; } v; v.f = f;
    unsigned u = v.u;
    return (unsigned short)((u + 0x7FFF + ((u >> 16) & 1)) >> 16);  // RNE
}

// prep: [0,247500) xp+zero | +13824 Wp2 | +882 tbl | +451584 out=bias init
__global__ __launch_bounds__(256)
void prep(const float* __restrict__ x, const float* __restrict__ conv,
          const float* __restrict__ bias,
          unsigned short* __restrict__ ws16, float* __restrict__ out) {
    int g = blockIdx.x * 256 + threadIdx.x;
    if (g < 247500) {
        unsigned short vals[8];
#pragma unroll
        for (int c = 0; c < 8; ++c) vals[c] = 0;
        if (g < 245000) {
            int b  = g / 122500;
            int r  = g - b * 122500;
            int uv = r / 2500;
            int p  = r - uv * 2500;
            int hh = p / 50, ww = p - hh * 50;
            int h = hh - 1, w = ww - 1;
            if (((unsigned)h < 48u) && ((unsigned)w < 48u)) {
                const float* xb = x + ((size_t)b * 8 * 49 + uv) * 2304 + h * 48 + w;
#pragma unroll
                for (int c = 0; c < 8; ++c) vals[c] = f2bf(xb[(size_t)c * CSTRIDE]);
            }
        }
        *(short8*)(ws16 + (size_t)g * 8) = *(const short8*)vals;   // incl. zero slice
        return;
    }
    g -= 247500;
    if (g < 13824) {                          // Wp2: 27 aslots * 512 elems
        int as   = g >> 9;
        int r    = g & 511;
        int lane = r >> 3, j = r & 7;
        int m = lane & 15, q = lane >> 4;
        int o = m & 7, d = m >> 3;
        int i0i1 = as / 3, i3 = as - 3 * i0i1;
        int i2 = q - d;
        unsigned short v = 0;
        if ((unsigned)i2 < 3u)
            v = f2bf(conv[o * 648 + ((i0i1 * 3 + i2) * 3 + i3) * 8 + j]);
        ws16[WP_OFF / 2 + g] = v;
        return;
    }
    g -= 13824;
    if (g < 882) {                            // tbl[img 98][k 9]
        int img = g / 9, k = g - img * 9;
        int b   = img / 49, uv = img - b * 49;
        int u   = uv / 7,   v  = uv - u * 7;
        int entry = ZS_OFF;                   // default: zero slice, i0i1=0
        int cnt = 0;
        for (int i01 = 0; i01 < 9; ++i01) {
            int i0 = i01 / 3, i1 = i01 - 3 * i0;
            int uu = u + i0 - 1, vv = v + i1 - 1;
            if (((unsigned)uu < 7u) && ((unsigned)vv < 7u)) {
                if (cnt == k)
                    entry = (((b * 7 + uu) * 7 + vv) * 40000) | (i01 << 22);
                ++cnt;
            }
        }
        ((int*)((char*)ws16 + WT_OFF))[g] = entry;
        return;
    }
    g -= 882;
    if (g < 451584) {                         // out := bias (float4 groups)
        int plane = g / 28224;                // (b*8+o), 28224 float4 per plane
        float bv = bias[plane & 7];
        f32x4 val = (f32x4){bv, bv, bv, bv};
        ((f32x4*)out)[g] = val;
    }
}

// Main: grid (18, 98, 2), 128 thr = 2 waves; wave = 2 dtiles, half the slices.
__global__ __launch_bounds__(128, 7)
void conv4d_mfma(const unsigned short* __restrict__ ws16,
                 float* __restrict__ out) {
    const int img = blockIdx.y;              // b*49 + uv
    const int par = blockIdx.z;              // slice parity
    const int b   = img / 49;
    const int uvr = img - b * 49;
    const int u   = uvr / 7;
    const int v   = uvr - u * 7;
    const int cu  = 3 - (u == 0) - (u == 6);
    const int cv  = 3 - (v == 0) - (v == 6);
    const int nv  = cu * cv;                 // 4, 6, or 9 valid slices
    const int count = (nv + 1 - par) >> 1;   // slices this wave: 2..5

    const int lane = threadIdx.x & 63;
    const int wave = threadIdx.x >> 6;
    const int n    = lane & 15;              // col within 16-tile
    const int quad = lane >> 4;              // j2 tap-row (B), k-group (A)

    // Wave's two dtiles: dt = widx*2 + {0,1}; dt -> (row-pair rp, col base w0).
    const int widx = blockIdx.x * 2 + wave;  // 0..35
    const int dt0  = widx * 2;
    const int rp0  = dt0 / 3,        w00 = (dt0 - 3 * rp0) * 16;
    const int dt1  = dt0 + 1;
    const int rp1  = dt1 / 3,        w01 = (dt1 - 3 * rp1) * 16;

    const int myoff0 = ((rp0 * 2 + quad) * 50 + w00 + n) * 16;
    const int myoff1 = ((rp1 * 2 + quad) * 50 + w01 + n) * 16;

    const char* base0  = (const char*)ws16;
    const char* wpb    = base0 + WP_OFF;
    const int   lane16 = lane * 16;

    // Hoist this parity's slice-table entries (stride 2, clamped in-bounds).
    const int* tblp = (const int*)(base0 + WT_OFF) + img * 9;
    int t[5];
#pragma unroll
    for (int i = 0; i < 5; ++i) {
        int idx = par + 2 * i;
        t[i] = tblp[idx > 8 ? 8 : idx];
    }

    f32x4 acc0 = (f32x4){0.f, 0.f, 0.f, 0.f};
    f32x4 acc1 = acc0;

#define SLICE(i)                                                               \
    {                                                                          \
        int e = t[i];                                                          \
        _Pragma("unroll")                                                      \
        for (int i3 = 0; i3 < 3; ++i3) {                                       \
            int tab = (e & 0x3FFFFF) + i3 * 16;                                \
            int wof = (((e >> 22) * 3 + i3) << 10);                            \
            short8 wf  = *(const short8*)(wpb + wof + lane16);                 \
            const char* xb = base0 + tab;                                      \
            short8 xf0 = *(const short8*)(xb + myoff0);                        \
            short8 xf1 = *(const short8*)(xb + myoff1);                        \
            acc0 = __builtin_amdgcn_mfma_f32_16x16x32_bf16(wf, xf0, acc0, 0, 0, 0); \
            acc1 = __builtin_amdgcn_mfma_f32_16x16x32_bf16(wf, xf1, acc1, 0, 0, 0); \
        }                                                                      \
    }

    SLICE(0);
    SLICE(1);
    if (count > 2) {
        SLICE(2);
        if (count > 3) {
            SLICE(3);
            if (count > 4) SLICE(4);
        }
    }
#undef SLICE

    // C/D: row m = quad*4 + r = o + 8d -> o = (quad&1)*4 + r, d = quad>>1.
    // Partial sum -> f32 HW atomic add (bias already in out).
    {
        const int d  = quad >> 1;
        const int oq = (quad & 1) * 4;
        float* obase = out + ((size_t)(b * 8 + oq) * 49 + uvr) * 2304;
        float* ob0 = obase + (rp0 * 2 + d) * 48 + w00 + n;
        float* ob1 = obase + (rp1 * 2 + d) * 48 + w01 + n;
#pragma unroll
        for (int r = 0; r < 4; ++r) {
            unsafeAtomicAdd(&ob0[(size_t)r * CSTRIDE], acc0[r]);
            unsafeAtomicAdd(&ob1[(size_t)r * CSTRIDE], acc1[r]);
        }
    }
}

extern "C" void kernel_launch(void* const* d_in, const int* in_sizes, int n_in,
                              void* d_out, int out_size, void* d_ws, size_t ws_size,
                              hipStream_t stream) {
    const float* x    = (const float*)d_in[0];
    const float* conv = (const float*)d_in[1];
    const float* bias = (const float*)d_in[2];
    float* out = (float*)d_out;
    unsigned short* ws16 = (unsigned short*)d_ws;

    int prep_threads = 247500 + 13824 + 882 + 451584;
    prep<<<dim3((prep_threads + 255) / 256), dim3(256), 0, stream>>>(
        x, conv, bias, ws16, out);
    conv4d_mfma<<<dim3(18, 98, 2), dim3(128), 0, stream>>>(ws16, out);
}

// Round 12
// 74.616 us; speedup vs baseline: 1.0970x; 1.0970x over previous
//
#include <hip/hip_runtime.h>

// Conv4D (2,8,7,7,48,48) fp32, 3x3x3x3 pad 1, 8->8 ch — bf16 MFMA implicit GEMM.
// R11 = R8b revert (best measured: 74.88 µs). Full-M packing: C rows m = o + 8d
// encode (out-ch o, out-row h+d); B taps j2 = i2+d span quad=0..3, so K per
// (u,v)-slice = 4x3x8 = 96 = exactly 3 chunks of 16x16x32 — no padded tail,
// all 16 M rows used. Register-hoisted 9-entry uniform slice table,
// fully-unrolled 12/+6/+9 chunk sections, no LDS, no barriers.
// R9 (4 dtiles/wave) and R10 (K-split+atomics) both regressed; this structure
// is the measured local optimum.
//
// d_ws layout (re-poisoned each launch; fully rewritten by prep):
//   [0,       3920000)  xp: bf16 x as [b][uv 49][hh 50][ww 50][c 8], halo zeros
//   [3920000, 3960000)  zero slice (40 KB) backing invalid (u,v) slices
//   [3960000, 3987648)  Wp2: A-frags [aslot 27 = i0i1*3+i3][lane 64][j 8] bf16
//                       Wp2[as][lane][j] = W[o=m&7, i0i1, i2=q-d, i3, c=j],
//                       m=lane&15, q=lane>>4, d=m>>3; zero if q-d not in 0..2
//   [3987648, 3991176)  tbl: [img 98][k 9] i32 = uvbase | (i0i1 << 22)

typedef __attribute__((ext_vector_type(8))) short short8;
typedef __attribute__((ext_vector_type(4))) float f32x4;

#define CSTRIDE (49 * 2304)
#define ZS_OFF  3920000
#define WP_OFF  3960000
#define WT_OFF  3987648

__device__ __forceinline__ unsigned short f2bf(float f) {
    union { float f; unsigned u; } v; v.f = f;
    unsigned u = v.u;
    return (unsigned short)((u + 0x7FFF + ((u >> 16) & 1)) >> 16);  // RNE
}

// prep: [0,247500) xp+zero | +13824 Wp2 | +882 tbl   (262206 threads)
__global__ __launch_bounds__(256)
void prep(const float* __restrict__ x, const float* __restrict__ conv,
          unsigned short* __restrict__ ws16) {
    int g = blockIdx.x * 256 + threadIdx.x;
    if (g < 247500) {
        unsigned short vals[8];
#pragma unroll
        for (int c = 0; c < 8; ++c) vals[c] = 0;
        if (g < 245000) {
            int b  = g / 122500;
            int r  = g - b * 122500;
            int uv = r / 2500;
            int p  = r - uv * 2500;
            int hh = p / 50, ww = p - hh * 50;
            int h = hh - 1, w = ww - 1;
            if (((unsigned)h < 48u) && ((unsigned)w < 48u)) {
                const float* xb = x + ((size_t)b * 8 * 49 + uv) * 2304 + h * 48 + w;
#pragma unroll
                for (int c = 0; c < 8; ++c) vals[c] = f2bf(xb[(size_t)c * CSTRIDE]);
            }
        }
        *(short8*)(ws16 + (size_t)g * 8) = *(const short8*)vals;   // incl. zero slice
        return;
    }
    g -= 247500;
    if (g < 13824) {                          // Wp2: 27 aslots * 512 elems
        int as   = g >> 9;
        int r    = g & 511;
        int lane = r >> 3, j = r & 7;
        int m = lane & 15, q = lane >> 4;
        int o = m & 7, d = m >> 3;
        int i0i1 = as / 3, i3 = as - 3 * i0i1;
        int i2 = q - d;
        unsigned short v = 0;
        if ((unsigned)i2 < 3u)
            v = f2bf(conv[o * 648 + ((i0i1 * 3 + i2) * 3 + i3) * 8 + j]);
        ws16[WP_OFF / 2 + g] = v;
        return;
    }
    g -= 13824;
    if (g < 882) {                            // tbl[img 98][k 9]
        int img = g / 9, k = g - img * 9;
        int b   = img / 49, uv = img - b * 49;
        int u   = uv / 7,   v  = uv - u * 7;
        int entry = ZS_OFF;                   // default: zero slice, i0i1=0
        int cnt = 0;
        for (int i01 = 0; i01 < 9; ++i01) {
            int i0 = i01 / 3, i1 = i01 - 3 * i0;
            int uu = u + i0 - 1, vv = v + i1 - 1;
            if (((unsigned)uu < 7u) && ((unsigned)vv < 7u)) {
                if (cnt == k)
                    entry = (((b * 7 + uu) * 7 + vv) * 40000) | (i01 << 22);
                ++cnt;
            }
        }
        ((int*)((char*)ws16 + WT_OFF))[g] = entry;
    }
}

// Main: grid (18, 98), 128 thr = 2 waves; wave = 2 dtiles (2 rows x 16 cols each).
__global__ __launch_bounds__(128, 4)
void conv4d_mfma(const unsigned short* __restrict__ ws16,
                 const float* __restrict__ bias,
                 float* __restrict__ out) {
    const int img = blockIdx.y;              // b*49 + uv
    const int b   = img / 49;
    const int uvr = img - b * 49;
    const int u   = uvr / 7;
    const int v   = uvr - u * 7;
    const int cu  = 3 - (u == 0) - (u == 6);
    const int cv  = 3 - (v == 0) - (v == 6);
    const int nchunk = cu * cv * 3;          // 12, 18, or 27 (exact, no tail)

    const int lane = threadIdx.x & 63;
    const int wave = threadIdx.x >> 6;
    const int n    = lane & 15;              // col within 16-tile (B col, A m-row)
    const int quad = lane >> 4;              // j2 tap-row (B), k-group (A)

    // Wave's two dtiles: dt = widx*2 + {0,1}; dt -> (row-pair rp, col base w0).
    const int widx = blockIdx.x * 2 + wave;  // 0..35
    const int dt0  = widx * 2;
    const int rp0  = dt0 / 3,        w00 = (dt0 - 3 * rp0) * 16;
    const int dt1  = dt0 + 1;
    const int rp1  = dt1 / 3,        w01 = (dt1 - 3 * rp1) * 16;

    // B per-lane offsets: row' = rp*2 + quad, col' = w0 + n (+ i3*16 via tab).
    const int myoff0 = ((rp0 * 2 + quad) * 50 + w00 + n) * 16;
    const int myoff1 = ((rp1 * 2 + quad) * 50 + w01 + n) * 16;

    const char* base0  = (const char*)ws16;
    const char* wpb    = base0 + WP_OFF;
    const int   lane16 = lane * 16;

    // Hoist the 9 uniform slice-table entries into registers.
    const int* tblp = (const int*)(base0 + WT_OFF) + img * 9;
    int t[9];
#pragma unroll
    for (int k = 0; k < 9; ++k) t[k] = tblp[k];

    f32x4 acc0 = (f32x4){0.f, 0.f, 0.f, 0.f};
    f32x4 acc1 = acc0;

#define CHUNK(c)                                                               \
    {                                                                          \
        int sl = (c) / 3, i3 = (c) % 3;                                        \
        int e   = t[sl];                                                       \
        int tab = (e & 0x3FFFFF) + i3 * 16;                                    \
        int wof = (((e >> 22) * 3 + i3) << 10);                                \
        short8 wf  = *(const short8*)(wpb + wof + lane16);                     \
        const char* xb = base0 + tab;                                          \
        short8 xf0 = *(const short8*)(xb + myoff0);                            \
        short8 xf1 = *(const short8*)(xb + myoff1);                            \
        acc0 = __builtin_amdgcn_mfma_f32_16x16x32_bf16(wf, xf0, acc0, 0, 0, 0);\
        acc1 = __builtin_amdgcn_mfma_f32_16x16x32_bf16(wf, xf1, acc1, 0, 0, 0);\
    }

    // Exact sections for nchunk in {12, 18, 27}.
#pragma unroll
    for (int c = 0; c < 12; ++c) CHUNK(c);
    if (nchunk > 12) {
#pragma unroll
        for (int c = 12; c < 18; ++c) CHUNK(c);
        if (nchunk > 18) {
#pragma unroll
            for (int c = 18; c < 27; ++c) CHUNK(c);
        }
    }
#undef CHUNK

    // C/D: row m = quad*4 + r = o + 8d -> o = (quad&1)*4 + r, d = quad>>1.
    // col = n. Out row = rp*2 + d, out col = w0 + n.
    {
        const int d  = quad >> 1;
        const int oq = (quad & 1) * 4;
        const f32x4 bb = *(const f32x4*)(bias + oq);
        float* obase = out + ((size_t)(b * 8 + oq) * 49 + uvr) * 2304;
        float* ob0 = obase + (rp0 * 2 + d) * 48 + w00 + n;
        float* ob1 = obase + (rp1 * 2 + d) * 48 + w01 + n;
#pragma unroll
        for (int r = 0; r < 4; ++r) {
            ob0[(size_t)r * CSTRIDE] = acc0[r] + bb[r];
            ob1[(size_t)r * CSTRIDE] = acc1[r] + bb[r];
        }
    }
}

extern "C" void kernel_launch(void* const* d_in, const int* in_sizes, int n_in,
                              void* d_out, int out_size, void* d_ws, size_t ws_size,
                              hipStream_t stream) {
    const float* x    = (const float*)d_in[0];
    const float* conv = (const float*)d_in[1];
    const float* bias = (const float*)d_in[2];
    float* out = (float*)d_out;
    unsigned short* ws16 = (unsigned short*)d_ws;

    prep<<<dim3((247500 + 13824 + 882 + 255) / 256), dim3(256), 0, stream>>>(x, conv, ws16);
    conv4d_mfma<<<dim3(18, 98), dim3(128), 0, stream>>>(ws16, bias, out);
}